// Round 7
// baseline (294.791 us; speedup 1.0000x reference)
//
#include <hip/hip_runtime.h>
#include <hip/hip_bf16.h>

#define B_ 4
#define LQ_ 2048
#define LK_ 2048
#define E_ 768
#define H_ 12
#define D_ 64
// SCALE * log2(e) folded into Q projection so attention uses bare exp2
#define QSCALE_ 0.04508422f

using short8 = __attribute__((ext_vector_type(8))) short;
using f32x4  = __attribute__((ext_vector_type(4))) float;
using f32x16 = __attribute__((ext_vector_type(16))) float;
using uint2v = __attribute__((ext_vector_type(2))) unsigned;

__device__ inline unsigned short f2bf(float f) {
    union { float f; unsigned u; } v; v.f = f;
    unsigned r = (v.u + 0x7FFFu + ((v.u >> 16) & 1u)) >> 16;
    return (unsigned short)r;
}
__device__ inline float bf2f(unsigned short u) {
    union { unsigned u; float f; } v; v.u = ((unsigned)u) << 16; return v.f;
}
// pack two fp32 -> two bf16 in one u32 (round-half-up)
__device__ inline unsigned pkbf(float a, float b) {
    union { float f; unsigned u; } x, y; x.f = a; y.f = b;
    return ((x.u + 0x8000u) >> 16) | ((y.u + 0x8000u) & 0xffff0000u);
}
// packed HW convert (v_cvt_pk_bf16_f32 on gfx950)
__device__ inline unsigned pkcvt(float a, float b) {
    float2 p; p.x = a; p.y = b;
    __hip_bfloat162 pb = __float22bfloat162_rn(p);
    union { __hip_bfloat162 h; unsigned u; } c; c.h = pb;
    return c.u;
}
// async global->LDS, 16B per lane; LDS dest = uniform base + lane*16
__device__ inline void gll16(const void* g, void* l) {
    __builtin_amdgcn_global_load_lds(
        (const __attribute__((address_space(1))) unsigned int*)g,
        (__attribute__((address_space(3))) unsigned int*)l, 16, 0, 0);
}

// ---------------- LayerNorm (both inputs in one launch): wave per row, fp32->bf16 --
__global__ __launch_bounds__(256) void ln_kernel(
    const float* __restrict__ xq, const float* __restrict__ xkv,
    const float* __restrict__ gq, const float* __restrict__ bq,
    const float* __restrict__ gk, const float* __restrict__ bk,
    unsigned short* __restrict__ yq, unsigned short* __restrict__ ykv)
{
    int wave = threadIdx.x >> 6, lane = threadIdx.x & 63;
    int row = blockIdx.x * 4 + wave;          // 0..16383
    const float* x; const float* g; const float* be; unsigned short* y;
    if (row < 8192) { x = xq; g = gq; be = bq; y = yq; }
    else { row -= 8192; x = xkv; g = gk; be = bk; y = ykv; }
    const float* xr = x + (size_t)row * E_;
    float4 v[3];
    float s = 0.f;
#pragma unroll
    for (int i = 0; i < 3; i++) {
        v[i] = *(const float4*)(xr + i * 256 + lane * 4);
        s += v[i].x + v[i].y + v[i].z + v[i].w;
    }
#pragma unroll
    for (int off = 32; off >= 1; off >>= 1) s += __shfl_xor(s, off);
    float mu = s * (1.0f / E_);
    float q = 0.f;
#pragma unroll
    for (int i = 0; i < 3; i++) {
        float dx = v[i].x - mu, dy = v[i].y - mu, dz = v[i].z - mu, dw = v[i].w - mu;
        q += dx * dx + dy * dy + dz * dz + dw * dw;
    }
#pragma unroll
    for (int off = 32; off >= 1; off >>= 1) q += __shfl_xor(q, off);
    float rstd = rsqrtf(q * (1.0f / E_) + 1e-5f);
    unsigned short* yr = y + (size_t)row * E_;
#pragma unroll
    for (int i = 0; i < 3; i++) {
        int c = i * 256 + lane * 4;
        float4 gv = *(const float4*)(g + c);
        float4 bv = *(const float4*)(be + c);
        ushort4 o;
        o.x = f2bf((v[i].x - mu) * rstd * gv.x + bv.x);
        o.y = f2bf((v[i].y - mu) * rstd * gv.y + bv.y);
        o.z = f2bf((v[i].z - mu) * rstd * gv.z + bv.z);
        o.w = f2bf((v[i].w - mu) * rstd * gv.w + bv.w);
        *(ushort4*)(yr + c) = o;
    }
}

// ---------------- transpose + cast all 3 weights in one launch --------------------
__global__ __launch_bounds__(256) void transpose3_kernel(
    const float* __restrict__ Wq, const float* __restrict__ Wkv, const float* __restrict__ Wo,
    unsigned short* __restrict__ WqT, unsigned short* __restrict__ WkvT, unsigned short* __restrict__ WoT)
{
    __shared__ float tile[32][33];
    int z = blockIdx.z;
    const float* in; unsigned short* out; int C;
    if (z == 0)      { in = Wq;  out = WqT;  C = E_; }
    else if (z == 1) { in = Wkv; out = WkvT; C = 2 * E_; }
    else             { in = Wo;  out = WoT;  C = E_; }
    int c0 = blockIdx.x * 32, r0 = blockIdx.y * 32;
    if (c0 >= C) return;
    int tx = threadIdx.x & 31, ty = threadIdx.x >> 5;
#pragma unroll
    for (int i = 0; i < 32; i += 8)
        tile[ty + i][tx] = in[(size_t)(r0 + ty + i) * C + c0 + tx];
    __syncthreads();
#pragma unroll
    for (int i = 0; i < 32; i += 8)
        out[(size_t)(c0 + ty + i) * E_ + r0 + tx] = f2bf(tile[tx][ty + i]);
}

// ---------------- merged Q + KV projection GEMM (BM=128), gll + XOR swizzle -------
// grid (64 m-tiles [XCD-stationary A], 18 n-tiles: y<6 -> Q, y>=6 -> KV)
#define BK 64
__global__ __launch_bounds__(256) void qkv_gemm(
    const unsigned short* __restrict__ Aq, const unsigned short* __restrict__ Akv,
    const unsigned short* __restrict__ WqT, const unsigned short* __restrict__ WkvT,
    unsigned short* __restrict__ outQ, unsigned short* __restrict__ outK,
    unsigned short* __restrict__ outV,
    const float* __restrict__ freqs_q, const float* __restrict__ freqs_k)
{
    __shared__ __align__(16) unsigned short smem[128 * 136];
    auto Asm = (unsigned short (*)[BK])smem;               // [128][64]
    auto Bsm = (unsigned short (*)[BK])(smem + 128 * BK);  // [128][64]

    bool isQ = blockIdx.y < 6;
    const unsigned short* A  = isQ ? Aq : Akv;
    const unsigned short* Bt = isQ ? WqT : WkvT;
    int bn = (isQ ? blockIdx.y : blockIdx.y - 6) * 128;
    int bm = blockIdx.x * 128;

    int tid = threadIdx.x;
    int wave = tid >> 6, lane = tid & 63;
    int quad = lane >> 4, l16 = lane & 15;
    int waveM = (wave >> 1) * 64, waveN = (wave & 1) * 64;
    int ro = lane >> 3, cx = lane & 7;
    int sco = ((cx ^ ro) * 8);

    f32x4 acc[4][4] = {};

    for (int k0 = 0; k0 < E_; k0 += BK) {
        const unsigned short* Ag = A + (size_t)(bm + wave * 32 + ro) * E_ + k0 + sco;
        const unsigned short* Bg = Bt + (size_t)(bn + wave * 32 + ro) * E_ + k0 + sco;
#pragma unroll
        for (int i = 0; i < 4; i++) {
            gll16(Ag + (size_t)(i * 8) * E_, &Asm[wave * 32 + i * 8][0]);
            gll16(Bg + (size_t)(i * 8) * E_, &Bsm[wave * 32 + i * 8][0]);
        }
        __syncthreads();
#pragma unroll
        for (int kk = 0; kk < BK; kk += 32) {
            short8 fa[4], fb[4];
#pragma unroll
            for (int t = 0; t < 4; t++) {
                int pos = ((quad + (kk >> 3)) ^ (l16 & 7)) * 8;
                fa[t] = *(const short8*)(&Asm[waveM + t * 16 + l16][pos]);
                fb[t] = *(const short8*)(&Bsm[waveN + t * 16 + l16][pos]);
            }
#pragma unroll
            for (int mt = 0; mt < 4; mt++)
#pragma unroll
                for (int nt = 0; nt < 4; nt++)
                    acc[mt][nt] = __builtin_amdgcn_mfma_f32_16x16x32_bf16(fa[mt], fb[nt], acc[mt][nt], 0, 0, 0);
        }
        __syncthreads();
    }

    if (!isQ && bn >= E_) {
        // ---- V block: transposed store via LDS bounce -> Vt[bh][d][key] ----
        auto T = (unsigned short (*)[136])smem;
#pragma unroll
        for (int mt = 0; mt < 4; mt++) {
#pragma unroll
            for (int nt = 0; nt < 4; nt++) {
                int ml = waveM + mt * 16 + quad * 4;
                int nl = waveN + nt * 16 + l16;
                *(unsigned*)&T[nl][ml]     = pkbf(acc[mt][nt][0], acc[mt][nt][1]);
                *(unsigned*)&T[nl][ml + 2] = pkbf(acc[mt][nt][2], acc[mt][nt][3]);
            }
        }
        __syncthreads();
        int nnbase = bn - E_;
        int bb = bm >> 11, l0 = bm & (LQ_ - 1);
#pragma unroll
        for (int it = 0; it < 8; it++) {
            int row = it * 16 + (tid >> 4);
            int hh = (nnbase + row) >> 6, dd = (nnbase + row) & 63;
            short8 v = *(const short8*)&T[row][(tid & 15) * 8];
            *(short8*)(outV + (((size_t)bb * H_ + hh) * D_ + dd) * LK_ + l0 + (tid & 15) * 8) = v;
        }
        return;
    }

    float scl = isQ ? QSCALE_ : 1.0f;
    const float* fr = isQ ? freqs_q : freqs_k;
    unsigned short* dst = isQ ? outQ : outK;
#pragma unroll
    for (int mt = 0; mt < 4; mt++) {
#pragma unroll
        for (int nt = 0; nt < 4; nt++) {
#pragma unroll
            for (int r = 0; r < 4; r++) {
                int m = bm + waveM + mt * 16 + quad * 4 + r;
                int n = bn + waveN + nt * 16 + l16;
                float v = acc[mt][nt][r];
                int l = m & (LQ_ - 1), bb = m >> 11;
                float partner = __shfl_xor(v, 1);
                int h = n >> 6, dd = n & 63;
                const float* f = fr + ((size_t)l * 32 + (dd >> 1)) * 2;
                float f0 = f[0], f1 = f[1];
                float o = ((dd & 1) == 0) ? (v * f0 - partner * f1)
                                          : (partner * f1 + v * f0);
                dst[(((size_t)bb * H_ + h) * LQ_ + l) * D_ + dd] = f2bf(o * scl);
            }
        }
    }
}

// ---------------- flash attention: no-shuffle PV, key-split z=2, dbuf gll ---------
// grid (48 bh [XCD-stationary K/V], 16 q-blocks, 2 key-halves)
// Writes UNNORMALIZED bf16 partial O + f32 partial lsum; combine_kernel finishes.
__global__ __launch_bounds__(256, 5) void attn_kernel(
    const unsigned short* __restrict__ Qg, const unsigned short* __restrict__ Kg,
    const unsigned short* __restrict__ Vt,
    unsigned short* __restrict__ Op0, unsigned short* __restrict__ Op1,
    float* __restrict__ Lp)
{
    __shared__ unsigned short Ksm[2][64][64];   // [buf][key][d]   (chunk-swizzled)
    __shared__ unsigned short Vsm[2][64][64];   // [buf][d][key]   (chunk-swizzled)

    int tid = threadIdx.x;
    int wave = tid >> 6, lane = tid & 63;
    int l32 = lane & 31, hi = lane >> 5;
    int bh = blockIdx.x;
    int z = blockIdx.z;
    int qbase = blockIdx.y * 128 + wave * 32;
    int kt0 = z << 10;                          // z*1024

    const size_t head = (size_t)bh * LK_ * D_;
    const unsigned short* Qh = Qg + head;
    const unsigned short* Kh = Kg + head + (size_t)kt0 * D_;
    const unsigned short* Vh = Vt + head;       // [d][key]

    // Q fragments: B-operand [k=d][n=q]
    short8 qf[4];
#pragma unroll
    for (int dc = 0; dc < 4; dc++)
        qf[dc] = *(const short8*)(Qh + (size_t)(qbase + l32) * D_ + dc * 16 + hi * 8);

    f32x16 oacc[2] = {};
    float lsum = 0.f;

    int ro = lane >> 3, cx = lane & 7;
    int sco = ((cx ^ ro) * 8);
    int sw = l32 & 7;

    // stage tile 0 into buf 0
    {
        const unsigned short* Kp = Kh + (size_t)(wave * 16 + ro) * D_ + sco;
        const unsigned short* Vp = Vh + (size_t)(wave * 16 + ro) * LK_ + kt0 + sco;
        gll16(Kp,            &Ksm[0][wave * 16][0]);
        gll16(Kp + 8 * D_,   &Ksm[0][wave * 16 + 8][0]);
        gll16(Vp,            &Vsm[0][wave * 16][0]);
        gll16(Vp + 8 * LK_,  &Vsm[0][wave * 16 + 8][0]);
    }
    asm volatile("s_waitcnt vmcnt(0)" ::: "memory");

    int buf = 0;
    for (int it = 0; it < 16; it++, buf ^= 1) {
        if (it < 15) {
            int kn = (it + 1) * 64;
            const unsigned short* Kp = Kh + (size_t)(kn + wave * 16 + ro) * D_ + sco;
            const unsigned short* Vp = Vh + (size_t)(wave * 16 + ro) * LK_ + kt0 + kn + sco;
            gll16(Kp,           &Ksm[buf ^ 1][wave * 16][0]);
            gll16(Kp + 8 * D_,  &Ksm[buf ^ 1][wave * 16 + 8][0]);
            gll16(Vp,           &Vsm[buf ^ 1][wave * 16][0]);
            gll16(Vp + 8 * LK_, &Vsm[buf ^ 1][wave * 16 + 8][0]);
            asm volatile("s_waitcnt vmcnt(4)\ns_barrier" ::: "memory");
        } else {
            asm volatile("s_waitcnt vmcnt(0)\ns_barrier" ::: "memory");
        }

#pragma unroll
        for (int half = 0; half < 2; half++) {
            // S^T[key][q]: A = K rows (M=key), B = Q (N=q), k-dim = d
            f32x16 st = {};
#pragma unroll
            for (int dc = 0; dc < 4; dc++) {
                int pos = ((dc * 2 + hi) ^ sw) * 8;
                short8 kfr = *(const short8*)(&Ksm[buf][half * 32 + l32][pos]);
                st = __builtin_amdgcn_mfma_f32_32x32x16_bf16(kfr, qf[dc], st, 0, 0, 0);
            }
            // exp2 + packed bf16 convert; pks[t] = packed S-regs (2t,2t+1)
            unsigned pks[8];
#pragma unroll
            for (int t = 0; t < 8; t++) {
                float p0 = __builtin_amdgcn_exp2f(st[2 * t]);
                float p1 = __builtin_amdgcn_exp2f(st[2 * t + 1]);
                lsum += p0 + p1;
                pks[t] = pkcvt(p0, p1);
            }
            // PV with NO cross-lane transform: A-frag = pks[4kk..4kk+3] verbatim.
            // Slot(hi,j) then holds physical key kk*16 + {4hi+j, 8+4hi+(j-4)};
            // B-frag loads V at exactly those keys: ds_read_b64 at cols
            // half*32 + kk*16 + 4hi and +8.
#pragma unroll
            for (int kk = 0; kk < 2; kk++) {
                union { unsigned u[4]; short8 s; } pf;
                pf.u[0] = pks[4 * kk + 0]; pf.u[1] = pks[4 * kk + 1];
                pf.u[2] = pks[4 * kk + 2]; pf.u[3] = pks[4 * kk + 3];
                int ch0 = half * 4 + kk * 2;
#pragma unroll
                for (int dt = 0; dt < 2; dt++) {
                    int row = dt * 32 + l32;
                    int e0 = ((ch0 ^ sw) * 8) + hi * 4;
                    int e1 = (((ch0 + 1) ^ sw) * 8) + hi * 4;
                    union { uint2v u2[2]; short8 s; } vf;
                    vf.u2[0] = *(const uint2v*)(&Vsm[buf][row][e0]);
                    vf.u2[1] = *(const uint2v*)(&Vsm[buf][row][e1]);
                    oacc[dt] = __builtin_amdgcn_mfma_f32_32x32x16_bf16(pf.s, vf.s, oacc[dt], 0, 0, 0);
                }
            }
        }
        // WAR fence: no vmcnt drain — prefetch stays in flight.
        asm volatile("s_waitcnt lgkmcnt(0)\ns_barrier" ::: "memory");
    }

    // epilogue: partial row sums + unnormalized partial O
    lsum += __shfl_xor(lsum, 32);
    if (hi == 0)
        Lp[((size_t)z * 48 + bh) * LQ_ + qbase + l32] = lsum;
    unsigned short* Od = z ? Op1 : Op0;
#pragma unroll
    for (int reg = 0; reg < 16; reg++) {
        int ql = (reg & 3) + 8 * (reg >> 2) + 4 * hi;
        int q = qbase + ql;
        size_t base = ((size_t)bh * LQ_ + q) * D_;
#pragma unroll
        for (int dt = 0; dt < 2; dt++)
            Od[base + dt * 32 + l32] = f2bf(oacc[dt][reg]);
    }
}

// ---------------- combine: O = (O0+O1)/(l0+l1), relayout to [b][q][h*64+d] --------
__global__ __launch_bounds__(256) void combine_kernel(
    const unsigned short* __restrict__ Op0, const unsigned short* __restrict__ Op1,
    const float* __restrict__ Lp, unsigned short* __restrict__ Ob)
{
    const int PL = 48 * LQ_;
    int t = blockIdx.x * 256 + threadIdx.x;   // 786432 threads
    int chunk = t & 7;
    int bhq = t >> 3;
    size_t o = (size_t)bhq * D_ + chunk * 8;
    short8 a = *(const short8*)(Op0 + o);
    short8 b = *(const short8*)(Op1 + o);
    float inv = 1.f / (Lp[bhq] + Lp[PL + bhq]);
    int bh = bhq >> 11, q = bhq & (LQ_ - 1);
    int bb = bh / H_, h = bh % H_;
    short8 r;
#pragma unroll
    for (int j = 0; j < 8; j++) {
        float s = bf2f((unsigned short)a[j]) + bf2f((unsigned short)b[j]);
        r[j] = (short)f2bf(s * inv);
    }
    *(short8*)(Ob + ((size_t)(bb * LQ_ + q)) * E_ + h * D_ + chunk * 8) = r;
}

// ---------------- O-projection GEMM (BM=64): out = gain*(Ob @ Wo^T + bo) ----------
__global__ __launch_bounds__(256) void o_gemm(
    const unsigned short* __restrict__ A, const unsigned short* __restrict__ Bt,
    float* __restrict__ outF, const float* __restrict__ bo, const float* __restrict__ gain)
{
    __shared__ __align__(16) unsigned short smem[64 * BK + 128 * BK];
    auto Asm = (unsigned short (*)[BK])smem;
    auto Bsm = (unsigned short (*)[BK])(smem + 64 * BK);
    int tid = threadIdx.x;
    int wave = tid >> 6, lane = tid & 63;
    int quad = lane >> 4, l16 = lane & 15;
    int waveM = (wave >> 1) * 32, waveN = (wave & 1) * 64;
    int bm = blockIdx.x * 64, bn = blockIdx.y * 128;
    int ro = lane >> 3, cx = lane & 7;
    int sco = ((cx ^ ro) * 8);

    f32x4 acc[2][4] = {};

    for (int k0 = 0; k0 < E_; k0 += BK) {
        const unsigned short* Ag = A + (size_t)(bm + wave * 16 + ro) * E_ + k0 + sco;
        const unsigned short* Bg = Bt + (size_t)(bn + wave * 32 + ro) * E_ + k0 + sco;
#pragma unroll
        for (int i = 0; i < 2; i++)
            gll16(Ag + (size_t)(i * 8) * E_, &Asm[wave * 16 + i * 8][0]);
#pragma unroll
        for (int i = 0; i < 4; i++)
            gll16(Bg + (size_t)(i * 8) * E_, &Bsm[wave * 32 + i * 8][0]);
        __syncthreads();
#pragma unroll
        for (int kk = 0; kk < BK; kk += 32) {
            short8 fa[2], fb[4];
#pragma unroll
            for (int t = 0; t < 4; t++) {
                int pos = ((quad + (kk >> 3)) ^ (l16 & 7)) * 8;
                if (t < 2) fa[t] = *(const short8*)(&Asm[waveM + t * 16 + l16][pos]);
                fb[t] = *(const short8*)(&Bsm[waveN + t * 16 + l16][pos]);
            }
#pragma unroll
            for (int mt = 0; mt < 2; mt++)
#pragma unroll
                for (int nt = 0; nt < 4; nt++)
                    acc[mt][nt] = __builtin_amdgcn_mfma_f32_16x16x32_bf16(fa[mt], fb[nt], acc[mt][nt], 0, 0, 0);
        }
        __syncthreads();
    }

    float gg = gain[0];
#pragma unroll
    for (int mt = 0; mt < 2; mt++)
#pragma unroll
        for (int nt = 0; nt < 4; nt++)
#pragma unroll
            for (int r = 0; r < 4; r++) {
                int m = bm + waveM + mt * 16 + quad * 4 + r;
                int n = bn + waveN + nt * 16 + l16;
                outF[(size_t)m * E_ + n] = gg * (acc[mt][nt][r] + bo[n]);
            }
}

extern "C" void kernel_launch(void* const* d_in, const int* in_sizes, int n_in,
                              void* d_out, int out_size, void* d_ws, size_t ws_size,
                              hipStream_t stream)
{
    const float* x_q     = (const float*)d_in[0];
    const float* x_kv    = (const float*)d_in[1];
    const float* freqs_q = (const float*)d_in[2];
    const float* freqs_k = (const float*)d_in[3];
    const float* Wq      = (const float*)d_in[4];
    const float* Wkv     = (const float*)d_in[5];
    const float* Wo      = (const float*)d_in[6];
    const float* bo      = (const float*)d_in[7];
    const float* ln_q_g  = (const float*)d_in[8];
    const float* ln_q_b  = (const float*)d_in[9];
    const float* ln_kv_g = (const float*)d_in[10];
    const float* ln_kv_b = (const float*)d_in[11];
    const float* gain    = (const float*)d_in[12];
    float* out = (float*)d_out;

    unsigned short* ws = (unsigned short*)d_ws;
    const size_t SZ = (size_t)B_ * LQ_ * E_;  // 6291456
    unsigned short* xq_ln  = ws;               // later: Ob (combine output)
    unsigned short* xkv_ln = xq_ln + SZ;       // later: Opart z=0
    unsigned short* Qb     = xkv_ln + SZ;
    unsigned short* Kb     = Qb + SZ;
    unsigned short* Vt     = Kb + SZ;          // filled transposed by KV-GEMM
    unsigned short* WqT    = Vt + SZ;
    unsigned short* WkvT   = WqT + E_ * E_;
    unsigned short* WoT    = WkvT + 2 * E_ * E_;
    unsigned short* Opz1   = WoT + E_ * E_;    // Opart z=1 (SZ shorts)
    float*          Lp     = (float*)(Opz1 + SZ);  // [2][48][2048] f32
    unsigned short* Opz0   = xkv_ln;
    unsigned short* Ob     = xq_ln;

    ln_kernel<<<4096, 256, 0, stream>>>(x_q, x_kv, ln_q_g, ln_q_b, ln_kv_g, ln_kv_b,
                                        xq_ln, xkv_ln);
    transpose3_kernel<<<dim3(48, 24, 3), 256, 0, stream>>>(Wq, Wkv, Wo, WqT, WkvT, WoT);
    qkv_gemm<<<dim3(64, 18), 256, 0, stream>>>(xq_ln, xkv_ln, WqT, WkvT,
                                               Qb, Kb, Vt, freqs_q, freqs_k);
    attn_kernel<<<dim3(48, 16, 2), 256, 0, stream>>>(Qb, Kb, Vt, Opz0, Opz1, Lp);
    combine_kernel<<<3072, 256, 0, stream>>>(Opz0, Opz1, Lp, Ob);
    o_gemm<<<dim3(128, 6), 256, 0, stream>>>(Ob, WoT, out, bo, gain);
}